// Round 18
// baseline (100.091 us; speedup 1.0000x reference)
//
#include <hip/hip_runtime.h>
#include <hip/hip_bf16.h>
#include <stdint.h>

#define BSZ 64
#define NRG 36
#define VD  2048
#define QD  1024
#define CS  512
#define RD  256
#define KP  2080                 // 2052 padded to 32
#define MR  (BSZ*NRG)            // 2304
#define TRI  666                 // upper-triangle pairs (i<=j) per batch
#define TRIQ 768                 // padded per-batch rows: 4 chunks of 192
#define NXB 2340                 // Xcg transpose blocks: 65 k-tiles x 36 row-blocks

typedef __bf16 bf16x8 __attribute__((ext_vector_type(8)));
typedef float  f32x4  __attribute__((ext_vector_type(4)));

static __device__ __forceinline__ f32x4 mfma16(bf16x8 a, bf16x8 b, f32x4 c) {
    return __builtin_amdgcn_mfma_f32_16x16x32_bf16(a, b, c, 0, 0, 0);
}

// async global->LDS, 16B per lane (dest = wave-uniform base + lane*16)
static __device__ __forceinline__ void load_lds16(const __bf16* g, __bf16* l) {
    __builtin_amdgcn_global_load_lds(
        (const __attribute__((address_space(1))) uint32_t*)(const void*)g,
        (__attribute__((address_space(3))) uint32_t*)(void*)l,
        16, 0, 0);
}

// ---- merged prep: Xcg g-major transpose, 3 g-major weights, lut, qproj ----
__global__ __launch_bounds__(256) void k_prep(
    const float* __restrict__ X, const float* __restrict__ pos,
    const float* __restrict__ Wv, const float* __restrict__ W1,
    const float* __restrict__ W2,
    const float* __restrict__ Q, const float* __restrict__ Wq,
    const float* __restrict__ bq,
    __bf16* __restrict__ Xcg, __bf16* __restrict__ Wvg,
    __bf16* __restrict__ W1g, __bf16* __restrict__ W2g,
    int* __restrict__ lut, float* __restrict__ Qp)
{
    __shared__ float ld[32 * 65];
    int id = blockIdx.x;
    if (id < NXB) {  // ---- Xcg[g][MR][8] <- [X|pos|0], LDS transpose ----
        int kt = id / 36, mb = id - kt * 36;
        int m0 = mb * 64;
        int r  = threadIdx.x >> 2;
        int kq = threadIdx.x & 3;
        int kbase = kt * 32 + kq * 8;
        float v[8];
        if (kbase + 7 < VD) {
            f32x4 a = *(const f32x4*)(X + (size_t)(m0 + r) * VD + kbase);
            f32x4 c = *(const f32x4*)(X + (size_t)(m0 + r) * VD + kbase + 4);
            v[0]=a[0]; v[1]=a[1]; v[2]=a[2]; v[3]=a[3];
            v[4]=c[0]; v[5]=c[1]; v[6]=c[2]; v[7]=c[3];
        } else {
            #pragma unroll
            for (int e = 0; e < 8; ++e) {
                int k = kbase + e;
                v[e] = (k < VD) ? X[(size_t)(m0 + r) * VD + k]
                     : (k < VD + 4 ? pos[(size_t)(m0 + r) * 4 + (k - VD)] : 0.f);
            }
        }
        #pragma unroll
        for (int e = 0; e < 8; ++e) ld[(kq * 8 + e) * 65 + r] = v[e];
        __syncthreads();
        int gl = threadIdx.x >> 6, rr = threadIdx.x & 63;
        bf16x8 o;
        #pragma unroll
        for (int e = 0; e < 8; ++e) o[e] = (__bf16)ld[(gl * 8 + e) * 65 + rr];
        *(bf16x8*)(Xcg + ((size_t)(kt * 4 + gl) * MR + m0 + rr) * 8) = o;
        return;
    }
    id -= NXB;
    if (id < 520 + 64 + 32) {    // ---- weight tile -> Wg[k/8][N][8] ----
        const float* W; __bf16* Wg; int K, N, nbx;
        if (id < 520)      {          W = Wv; Wg = Wvg; K = VD + 4; N = CS; nbx = CS / 64; }
        else if (id < 584) { id -= 520; W = W1; Wg = W1g; K = CS;     N = RD; nbx = RD / 64; }
        else               { id -= 584; W = W2; Wg = W2g; K = RD;     N = RD; nbx = RD / 64; }
        int bx = id % nbx, by = id / nbx;
        int g = by * 4 + (threadIdx.x >> 6);
        int n = bx * 64 + (threadIdx.x & 63);
        bf16x8 v;
        #pragma unroll
        for (int e = 0; e < 8; ++e) {
            int k = g * 8 + e;
            v[e] = (__bf16)((k < K) ? W[(size_t)k * N + n] : 0.f);
        }
        *(bf16x8*)(Wg + ((size_t)g * N + n) * 8) = v;
        return;
    }
    id -= 616;
    if (id == 0) {               // ---- lut ----
        for (int t = threadIdx.x; t < TRIQ; t += 256) {
            int tt = (t < TRI) ? t : (TRI - 1);
            int i = 0;
            while (tt >= NRG - i) { tt -= NRG - i; ++i; }
            lut[t] = (i << 8) | (i + tt);
        }
        return;
    }
    id -= 1;                     // ---- qproj ----
    {
        int b   = id >> 3;
        int col = (id & 7) * 64 + (threadIdx.x & 63);
        int ks  = threadIdx.x >> 6;
        const float* q = Q  + (size_t)b * QD + ks * 256;
        const float* w = Wq + (size_t)(ks * 256) * CS + col;
        float a0 = 0.f, a1 = 0.f, a2 = 0.f, a3 = 0.f;
        #pragma unroll 4
        for (int k = 0; k < 256; k += 4) {
            a0 = fmaf(q[k],     w[(size_t)(k)     * CS], a0);
            a1 = fmaf(q[k + 1], w[(size_t)(k + 1) * CS], a1);
            a2 = fmaf(q[k + 2], w[(size_t)(k + 2) * CS], a2);
            a3 = fmaf(q[k + 3], w[(size_t)(k + 3) * CS], a3);
        }
        __shared__ float red[256];
        red[threadIdx.x] = a0 + a1 + a2 + a3;
        __syncthreads();
        if (ks == 0) {
            float v = red[threadIdx.x] + red[threadIdx.x + 64]
                    + red[threadIdx.x + 128] + red[threadIdx.x + 192] + bq[col];
            Qp[(size_t)b * CS + col] = fmaxf(v, 0.f);
        }
    }
}

// ---- G1: Xs = relu(Xc @ Wv + bv) + Qp[b], ring-4 LDS, counted vmcnt ----
__global__ __launch_bounds__(256) void k_g1(
    const __bf16* __restrict__ Xcg,  // [KP/8][MR][8]
    const __bf16* __restrict__ Wvg,  // [KP/8][CS][8]
    const float* __restrict__ bv,
    const float* __restrict__ Qp,    // [BSZ][CS]
    __bf16* __restrict__ Xs)         // [MR][CS]
{
    __shared__ __align__(16) __bf16 sA[4][4 * 64 * 8];
    __shared__ __align__(16) __bf16 sB[4][4 * 64 * 8];

    const int tid = threadIdx.x;
    const int lane = tid & 63;
    const int w = tid >> 6;
    const int wm = w & 1, wn = w >> 1;
    const int l15 = lane & 15, l4 = lane >> 4;
    const int m0 = blockIdx.x * 64;
    const int n0 = blockIdx.y * 64;
    const int sg = tid >> 6;
    const int sr = tid & 63;

    auto stage = [&](int kt, int slot) {
        load_lds16(Xcg + ((size_t)(kt * 4 + sg) * MR + m0 + sr) * 8,
                   &sA[slot][0] + (size_t)tid * 8);
        load_lds16(Wvg + ((size_t)(kt * 4 + sg) * CS + n0 + sr) * 8,
                   &sB[slot][0] + (size_t)tid * 8);
    };

    constexpr int NKT = KP / 32;   // 65
    stage(0, 0);
    stage(1, 1);

    f32x4 acc[2][2] = {};
    for (int kt = 0; kt < NKT; ++kt) {
        if (kt + 2 < NKT) stage(kt + 2, (kt + 2) & 3);
        if (kt + 2 < NKT)      asm volatile("s_waitcnt vmcnt(4)" ::: "memory");
        else if (kt + 1 < NKT) asm volatile("s_waitcnt vmcnt(2)" ::: "memory");
        else                   asm volatile("s_waitcnt vmcnt(0)" ::: "memory");
        __builtin_amdgcn_s_barrier();

        const __bf16* a_base = &sA[kt & 3][0];
        const __bf16* b_base = &sB[kt & 3][0];
        bf16x8 af[2], bf[2];
        #pragma unroll
        for (int f = 0; f < 2; ++f)
            af[f] = *(const bf16x8*)(a_base + ((size_t)l4 * 64 + wm * 32 + f * 16 + l15) * 8);
        #pragma unroll
        for (int g = 0; g < 2; ++g)
            bf[g] = *(const bf16x8*)(b_base + ((size_t)l4 * 64 + wn * 32 + g * 16 + l15) * 8);
        __builtin_amdgcn_s_setprio(1);
        #pragma unroll
        for (int f = 0; f < 2; ++f)
            #pragma unroll
            for (int g = 0; g < 2; ++g)
                acc[f][g] = mfma16(af[f], bf[g], acc[f][g]);
        __builtin_amdgcn_s_setprio(0);
    }

    #pragma unroll
    for (int f = 0; f < 2; ++f) {
        int row0 = m0 + wm * 32 + f * 16 + l4 * 4;
        #pragma unroll
        for (int g = 0; g < 2; ++g) {
            int col = n0 + wn * 32 + g * 16 + l15;
            float bb = bv[col];
            #pragma unroll
            for (int r = 0; r < 4; ++r) {
                int row = row0 + r;
                float v = fmaxf(acc[f][g][r] + bb, 0.f) + Qp[(size_t)(row / NRG) * CS + col];
                Xs[(size_t)row * CS + col] = (__bf16)v;
            }
        }
    }
}

// ---- fused G2+G3 v11: Mf=4 waves (64r x 128c), 384 thr = 6 waves,
//      LDS reads/tile: 144 -> 96 (s1) / 72 (s2). Same M=192, grid 4x64. ----
__global__ __launch_bounds__(384, 1) void k_g23(
    const __bf16* __restrict__ Xs,   // [MR][CS]
    const __bf16* __restrict__ W1g,  // [CS/8][RD][8]
    const __bf16* __restrict__ W2g,  // [RD/8][RD][8]
    const float* __restrict__ b1,
    const float* __restrict__ b2,
    float* __restrict__ Out,         // [BSZ][NRG][NRG][RD]
    const int* __restrict__ lut)
{
    __shared__ __align__(16) __bf16 uni[32 * 192 * 8];     // 96 KB
    __shared__ __align__(16) __bf16 sW[4][4 * RD * 8];     // 4 x 16 KB ring

    const int tid = threadIdx.x;
    const int lane = tid & 63;
    const int w = tid >> 6;          // 6 waves
    const int mg = w >> 1;           // 0..2 : 64-row group
    const int nh = w & 1;            // 0..1 : 128-col half
    const int l15 = lane & 15, l4 = lane >> 4;
    const int b = blockIdx.y;
    const int r_base = blockIdx.x * 192;
    const char* sXc = (const char*)uni;

    // ---- stage Xs[b] -> sXs (coalesced, chunk-swizzle cp^(r&7)) ----
    {
        const __bf16* src = Xs + (size_t)b * NRG * CS;
        #pragma unroll
        for (int it = 0; it < 6; ++it) {
            int id = it * 384 + tid;          // 0..2303 chunks of 8 elems
            int r = id >> 6, cp = id & 63;
            bf16x8 v = *(const bf16x8*)(src + (size_t)r * CS + cp * 8);
            int ba = (r << 10) | ((cp ^ (r & 7)) << 4);
            *(bf16x8*)((char*)uni + ba) = v;
        }
    }
    // 4 row-fragments per wave: rows mg*64 + fm*16 + l15
    int iR[4], jR[4];
    #pragma unroll
    for (int fm = 0; fm < 4; ++fm) {
        int t = r_base + mg * 64 + fm * 16 + l15;
        int ij = lut[t];
        iR[fm] = ij >> 8;
        jR[fm] = ij & 255;
    }

    asm volatile("s_waitcnt lgkmcnt(0)" ::: "memory");
    __builtin_amdgcn_s_barrier();     // sXs ready

    // unified W tile stream: T0..15 = W1 tiles, T16..23 = W2 tiles
    auto stg_t = [&](int t) {
        if (tid < 256) {
            const __bf16* src = (t < 16) ? (W1g + (size_t)t * (RD * 32))
                                         : (W2g + (size_t)(t - 16) * (RD * 32));
            __bf16* dst = &sW[t & 3][0];
            #pragma unroll
            for (int it = 0; it < 4; ++it) {
                int c = tid + it * 256;
                load_lds16(src + (size_t)c * 8, dst + (size_t)c * 8);
            }
        }
    };

    stg_t(0);
    stg_t(1);

    // ---- stage 1: tiles T0..T15 (K=512); Mf=4 x Nf=8 = 32 MFMA/tile ----
    f32x4 acc[4][8] = {};
    for (int t = 0; t < 16; ++t) {
        stg_t(t + 2);
        asm volatile("s_waitcnt vmcnt(8)" ::: "memory");
        __builtin_amdgcn_s_barrier();
        const int kc = t * 4 + l4;
        bf16x8 af[4];
        #pragma unroll
        for (int fm = 0; fm < 4; ++fm) {
            bf16x8 xi = *(const bf16x8*)(sXc + ((iR[fm] << 10) | ((kc ^ (iR[fm] & 7)) << 4)));
            bf16x8 xj = *(const bf16x8*)(sXc + ((jR[fm] << 10) | ((kc ^ (jR[fm] & 7)) << 4)));
            #pragma unroll
            for (int e = 0; e < 8; ++e)
                af[fm][e] = (__bf16)((float)xi[e] * (float)xj[e]);
        }
        const __bf16* wb = &sW[t & 3][0];
        __builtin_amdgcn_s_setprio(1);
        #pragma unroll
        for (int g = 0; g < 8; ++g) {
            bf16x8 wf = *(const bf16x8*)(wb + ((size_t)l4 * RD + nh * 128 + g * 16 + l15) * 8);
            #pragma unroll
            for (int fm = 0; fm < 4; ++fm)
                acc[fm][g] = mfma16(af[fm], wf, acc[fm][g]);
        }
        __builtin_amdgcn_s_setprio(0);
    }

    __builtin_amdgcn_s_barrier();   // all done reading sXs (about to clobber)

    // ---- transition: H = relu(acc+b1) -> sH[kc2(32)][row(192)][8] ----
    #pragma unroll
    for (int g = 0; g < 8; ++g) {
        int col = nh * 128 + g * 16 + l15;
        float bb = b1[col];
        int kc2 = col >> 3, e = col & 7;
        #pragma unroll
        for (int fm = 0; fm < 4; ++fm) {
            int row0 = mg * 64 + fm * 16 + l4 * 4;
            #pragma unroll
            for (int r = 0; r < 4; ++r) {
                float v = fmaxf(acc[fm][g][r] + bb, 0.f);
                uni[((size_t)kc2 * 192 + row0 + r) * 8 + e] = (__bf16)v;
            }
        }
    }
    asm volatile("s_waitcnt lgkmcnt(0)" ::: "memory");
    __builtin_amdgcn_s_barrier();   // sH published

    // ---- stage 2: tiles T16..T23 (W2, K=256); 4 A-reads + 8 W-reads/tile ----
    f32x4 acc2[4][8] = {};
    for (int t = 16; t < 24; ++t) {
        if (t + 2 < 24) stg_t(t + 2);
        if (t + 2 < 24)      asm volatile("s_waitcnt vmcnt(8)" ::: "memory");
        else if (t + 1 < 24) asm volatile("s_waitcnt vmcnt(4)" ::: "memory");
        else                 asm volatile("s_waitcnt vmcnt(0)" ::: "memory");
        __builtin_amdgcn_s_barrier();
        const int kt = t - 16;
        bf16x8 ah[4];
        #pragma unroll
        for (int fm = 0; fm < 4; ++fm)
            ah[fm] = *(const bf16x8*)(uni + ((size_t)(kt * 4 + l4) * 192
                                             + mg * 64 + fm * 16 + l15) * 8);
        const __bf16* wb = &sW[t & 3][0];
        __builtin_amdgcn_s_setprio(1);
        #pragma unroll
        for (int g = 0; g < 8; ++g) {
            bf16x8 wf = *(const bf16x8*)(wb + ((size_t)l4 * RD + nh * 128 + g * 16 + l15) * 8);
            #pragma unroll
            for (int fm = 0; fm < 4; ++fm)
                acc2[fm][g] = mfma16(ah[fm], wf, acc2[fm][g]);
        }
        __builtin_amdgcn_s_setprio(0);
    }

    // ---- epilogue: acc2 -> LDS f32[96][256] -> 1KB contiguous stores ----
    // pass p covers fm = 2p, 2p+1: global row = mg*64 + p*32 + f16*16 + l4*4 + r
    float* uf = (float*)uni;
    float bias2[8];
    #pragma unroll
    for (int g = 0; g < 8; ++g) bias2[g] = b2[nh * 128 + g * 16 + l15];

    #pragma unroll
    for (int p = 0; p < 2; ++p) {
        __syncthreads();
        #pragma unroll
        for (int f16 = 0; f16 < 2; ++f16) {
            int fm = 2 * p + f16;
            #pragma unroll
            for (int g = 0; g < 8; ++g) {
                int col = nh * 128 + g * 16 + l15;
                #pragma unroll
                for (int r = 0; r < 4; ++r) {
                    int row96 = mg * 32 + f16 * 16 + l4 * 4 + r;
                    uf[(size_t)row96 * 256 + col] = fmaxf(acc2[fm][g][r] + bias2[g], 0.f);
                }
            }
        }
        __syncthreads();
        // 6 waves x 16 rows: one 1KB float4 store per row per mirror
        #pragma unroll
        for (int k = 0; k < 16; ++k) {
            int row96 = w * 16 + k;
            int gr = (row96 >> 5) * 64 + p * 32 + (row96 & 31);
            int t = r_base + gr;
            if (t < TRI) {
                int ij = lut[t];
                int i = ij >> 8, j = ij & 255;
                f32x4 v = *(const f32x4*)&uf[(size_t)row96 * 256 + lane * 4];
                *(f32x4*)(Out + ((size_t)((b * NRG + i) * NRG + j)) * RD + lane * 4) = v;
                *(f32x4*)(Out + ((size_t)((b * NRG + j) * NRG + i)) * RD + lane * 4) = v;
            }
        }
    }
}

extern "C" void kernel_launch(void* const* d_in, const int* in_sizes, int n_in,
                              void* d_out, int out_size, void* d_ws, size_t ws_size,
                              hipStream_t stream) {
    const float* X   = (const float*)d_in[0];
    const float* Q   = (const float*)d_in[1];
    const float* pos = (const float*)d_in[2];
    const float* Wv  = (const float*)d_in[3];
    const float* bv  = (const float*)d_in[4];
    const float* Wq  = (const float*)d_in[5];
    const float* bq  = (const float*)d_in[6];
    const float* W1  = (const float*)d_in[7];
    const float* b1  = (const float*)d_in[8];
    const float* W2  = (const float*)d_in[9];
    const float* b2  = (const float*)d_in[10];

    char* ws = (char*)d_ws;
    size_t off = 0;
    auto alloc = [&](size_t bytes) {
        char* p = ws + off;
        off = (off + bytes + 255) & ~(size_t)255;
        return p;
    };
    __bf16* Xcg = (__bf16*)alloc((size_t)(KP/8) * MR * 8 * 2);   // 9.6 MB g-major
    __bf16* Wvg = (__bf16*)alloc((size_t)(KP/8) * CS * 8 * 2);
    __bf16* W1g = (__bf16*)alloc((size_t)(CS/8) * RD * 8 * 2);
    __bf16* W2g = (__bf16*)alloc((size_t)(RD/8) * RD * 8 * 2);
    float*  Qp  = (float*) alloc((size_t)BSZ * CS * 4);
    __bf16* Xs  = (__bf16*)alloc((size_t)MR * CS * 2);
    int*    lut = (int*)   alloc((size_t)TRIQ * 4);

    hipLaunchKernelGGL(k_prep, dim3(NXB + 616 + 1 + 512), dim3(256), 0, stream,
                       X, pos, Wv, W1, W2, Q, Wq, bq,
                       Xcg, Wvg, W1g, W2g, lut, Qp);
    hipLaunchKernelGGL(k_g1, dim3(MR/64, CS/64), dim3(256), 0, stream,
                       Xcg, Wvg, bv, Qp, Xs);
    hipLaunchKernelGGL(k_g23, dim3(TRIQ/192, BSZ), dim3(384), 0, stream,
                       Xs, W1g, W2g, b1, b2, (float*)d_out, (const int*)lut);
}

// Round 19
// 95.068 us; speedup vs baseline: 1.0528x; 1.0528x over previous
//
#include <hip/hip_runtime.h>
#include <hip/hip_bf16.h>
#include <stdint.h>

#define BSZ 64
#define NRG 36
#define VD  2048
#define QD  1024
#define CS  512
#define RD  256
#define KP  2080                 // 2052 padded to 32
#define MR  (BSZ*NRG)            // 2304
#define TRI  666                 // upper-triangle pairs (i<=j) per batch
#define TRIQ 768                 // padded per-batch rows: 4 chunks of 192
#define NXB 2340                 // Xcg transpose blocks: 65 k-tiles x 36 row-blocks

typedef __bf16 bf16x8 __attribute__((ext_vector_type(8)));
typedef float  f32x4  __attribute__((ext_vector_type(4)));

static __device__ __forceinline__ f32x4 mfma16(bf16x8 a, bf16x8 b, f32x4 c) {
    return __builtin_amdgcn_mfma_f32_16x16x32_bf16(a, b, c, 0, 0, 0);
}

// async global->LDS, 16B per lane (dest = wave-uniform base + lane*16)
static __device__ __forceinline__ void load_lds16(const __bf16* g, __bf16* l) {
    __builtin_amdgcn_global_load_lds(
        (const __attribute__((address_space(1))) uint32_t*)(const void*)g,
        (__attribute__((address_space(3))) uint32_t*)(void*)l,
        16, 0, 0);
}

// ---- merged prep: Xcg g-major transpose, 3 g-major weights, lut, qproj ----
__global__ __launch_bounds__(256) void k_prep(
    const float* __restrict__ X, const float* __restrict__ pos,
    const float* __restrict__ Wv, const float* __restrict__ W1,
    const float* __restrict__ W2,
    const float* __restrict__ Q, const float* __restrict__ Wq,
    const float* __restrict__ bq,
    __bf16* __restrict__ Xcg, __bf16* __restrict__ Wvg,
    __bf16* __restrict__ W1g, __bf16* __restrict__ W2g,
    int* __restrict__ lut, float* __restrict__ Qp)
{
    __shared__ float ld[32 * 65];      // padded transpose buffer (8.3 KB)
    int id = blockIdx.x;
    if (id < NXB) {  // ---- Xcg[g][MR][8] <- [X|pos|0], LDS transpose ----
        int kt = id / 36, mb = id - kt * 36;
        int m0 = mb * 64;
        int r  = threadIdx.x >> 2;       // 0..63 row
        int kq = threadIdx.x & 3;        // 0..3  8-elem k-quad
        int kbase = kt * 32 + kq * 8;
        float v[8];
        if (kbase + 7 < VD) {            // all kt <= 63
            f32x4 a = *(const f32x4*)(X + (size_t)(m0 + r) * VD + kbase);
            f32x4 c = *(const f32x4*)(X + (size_t)(m0 + r) * VD + kbase + 4);
            v[0]=a[0]; v[1]=a[1]; v[2]=a[2]; v[3]=a[3];
            v[4]=c[0]; v[5]=c[1]; v[6]=c[2]; v[7]=c[3];
        } else {                         // kt == 64: pos + zero pad
            #pragma unroll
            for (int e = 0; e < 8; ++e) {
                int k = kbase + e;
                v[e] = (k < VD) ? X[(size_t)(m0 + r) * VD + k]
                     : (k < VD + 4 ? pos[(size_t)(m0 + r) * 4 + (k - VD)] : 0.f);
            }
        }
        #pragma unroll
        for (int e = 0; e < 8; ++e) ld[(kq * 8 + e) * 65 + r] = v[e];
        __syncthreads();
        int gl = threadIdx.x >> 6, rr = threadIdx.x & 63;
        bf16x8 o;
        #pragma unroll
        for (int e = 0; e < 8; ++e) o[e] = (__bf16)ld[(gl * 8 + e) * 65 + rr];
        *(bf16x8*)(Xcg + ((size_t)(kt * 4 + gl) * MR + m0 + rr) * 8) = o;
        return;
    }
    id -= NXB;
    if (id < 520 + 64 + 32) {    // ---- weight tile -> Wg[k/8][N][8] ----
        const float* W; __bf16* Wg; int K, N, nbx;
        if (id < 520)      {          W = Wv; Wg = Wvg; K = VD + 4; N = CS; nbx = CS / 64; }
        else if (id < 584) { id -= 520; W = W1; Wg = W1g; K = CS;     N = RD; nbx = RD / 64; }
        else               { id -= 584; W = W2; Wg = W2g; K = RD;     N = RD; nbx = RD / 64; }
        int bx = id % nbx, by = id / nbx;
        int g = by * 4 + (threadIdx.x >> 6);
        int n = bx * 64 + (threadIdx.x & 63);
        bf16x8 v;
        #pragma unroll
        for (int e = 0; e < 8; ++e) {
            int k = g * 8 + e;
            v[e] = (__bf16)((k < K) ? W[(size_t)k * N + n] : 0.f);
        }
        *(bf16x8*)(Wg + ((size_t)g * N + n) * 8) = v;
        return;
    }
    id -= 616;
    if (id == 0) {               // ---- lut ----
        for (int t = threadIdx.x; t < TRIQ; t += 256) {
            int tt = (t < TRI) ? t : (TRI - 1);
            int i = 0;
            while (tt >= NRG - i) { tt -= NRG - i; ++i; }
            lut[t] = (i << 8) | (i + tt);
        }
        return;
    }
    id -= 1;                     // ---- qproj: 512 blocks, 4 chains/slice ----
    {
        int b   = id >> 3;
        int col = (id & 7) * 64 + (threadIdx.x & 63);
        int ks  = threadIdx.x >> 6;
        const float* q = Q  + (size_t)b * QD + ks * 256;
        const float* w = Wq + (size_t)(ks * 256) * CS + col;
        float a0 = 0.f, a1 = 0.f, a2 = 0.f, a3 = 0.f;
        #pragma unroll 4
        for (int k = 0; k < 256; k += 4) {
            a0 = fmaf(q[k],     w[(size_t)(k)     * CS], a0);
            a1 = fmaf(q[k + 1], w[(size_t)(k + 1) * CS], a1);
            a2 = fmaf(q[k + 2], w[(size_t)(k + 2) * CS], a2);
            a3 = fmaf(q[k + 3], w[(size_t)(k + 3) * CS], a3);
        }
        __shared__ float red[256];
        red[threadIdx.x] = a0 + a1 + a2 + a3;
        __syncthreads();
        if (ks == 0) {
            float v = red[threadIdx.x] + red[threadIdx.x + 64]
                    + red[threadIdx.x + 128] + red[threadIdx.x + 192] + bq[col];
            Qp[(size_t)b * CS + col] = fmaxf(v, 0.f);
        }
    }
}

// ---- G1: Xs = relu(Xc @ Wv + bv) + Qp[b], ring-4 LDS, counted vmcnt ----
// A staged from g-major Xcg: coalesced gload_lds
__global__ __launch_bounds__(256) void k_g1(
    const __bf16* __restrict__ Xcg,  // [KP/8][MR][8]
    const __bf16* __restrict__ Wvg,  // [KP/8][CS][8]
    const float* __restrict__ bv,
    const float* __restrict__ Qp,    // [BSZ][CS]
    __bf16* __restrict__ Xs)         // [MR][CS]
{
    __shared__ __align__(16) __bf16 sA[4][4 * 64 * 8];
    __shared__ __align__(16) __bf16 sB[4][4 * 64 * 8];

    const int tid = threadIdx.x;
    const int lane = tid & 63;
    const int w = tid >> 6;
    const int wm = w & 1, wn = w >> 1;
    const int l15 = lane & 15, l4 = lane >> 4;
    const int m0 = blockIdx.x * 64;
    const int n0 = blockIdx.y * 64;
    const int sg = tid >> 6;
    const int sr = tid & 63;

    auto stage = [&](int kt, int slot) {
        load_lds16(Xcg + ((size_t)(kt * 4 + sg) * MR + m0 + sr) * 8,
                   &sA[slot][0] + (size_t)tid * 8);
        load_lds16(Wvg + ((size_t)(kt * 4 + sg) * CS + n0 + sr) * 8,
                   &sB[slot][0] + (size_t)tid * 8);
    };

    constexpr int NKT = KP / 32;   // 65
    stage(0, 0);
    stage(1, 1);

    f32x4 acc[2][2] = {};
    for (int kt = 0; kt < NKT; ++kt) {
        if (kt + 2 < NKT) stage(kt + 2, (kt + 2) & 3);
        if (kt + 2 < NKT)      asm volatile("s_waitcnt vmcnt(4)" ::: "memory");
        else if (kt + 1 < NKT) asm volatile("s_waitcnt vmcnt(2)" ::: "memory");
        else                   asm volatile("s_waitcnt vmcnt(0)" ::: "memory");
        __builtin_amdgcn_s_barrier();

        const __bf16* a_base = &sA[kt & 3][0];
        const __bf16* b_base = &sB[kt & 3][0];
        bf16x8 af[2], bf[2];
        #pragma unroll
        for (int f = 0; f < 2; ++f)
            af[f] = *(const bf16x8*)(a_base + ((size_t)l4 * 64 + wm * 32 + f * 16 + l15) * 8);
        #pragma unroll
        for (int g = 0; g < 2; ++g)
            bf[g] = *(const bf16x8*)(b_base + ((size_t)l4 * 64 + wn * 32 + g * 16 + l15) * 8);
        __builtin_amdgcn_s_setprio(1);
        #pragma unroll
        for (int f = 0; f < 2; ++f)
            #pragma unroll
            for (int g = 0; g < 2; ++g)
                acc[f][g] = mfma16(af[f], bf[g], acc[f][g]);
        __builtin_amdgcn_s_setprio(0);
    }

    #pragma unroll
    for (int f = 0; f < 2; ++f) {
        int row0 = m0 + wm * 32 + f * 16 + l4 * 4;
        #pragma unroll
        for (int g = 0; g < 2; ++g) {
            int col = n0 + wn * 32 + g * 16 + l15;
            float bb = bv[col];
            #pragma unroll
            for (int r = 0; r < 4; ++r) {
                int row = row0 + r;
                float v = fmaxf(acc[f][g][r] + bb, 0.f) + Qp[(size_t)(row / NRG) * CS + col];
                Xs[(size_t)row * CS + col] = (__bf16)v;
            }
        }
    }
}

// ---- fused G2+G3 (best config, R17): 768 thr / 12 waves / 1 block/CU,
//      unified 24-tile W stream, ring-4 sW, LDS-routed contiguous epilogue ----
__global__ __launch_bounds__(768, 1) void k_g23(
    const __bf16* __restrict__ Xs,   // [MR][CS]
    const __bf16* __restrict__ W1g,  // [CS/8][RD][8]
    const __bf16* __restrict__ W2g,  // [RD/8][RD][8]
    const float* __restrict__ b1,
    const float* __restrict__ b2,
    float* __restrict__ Out,         // [BSZ][NRG][NRG][RD]
    const int* __restrict__ lut)
{
    __shared__ __align__(16) __bf16 uni[32 * 192 * 8];     // 96 KB
    __shared__ __align__(16) __bf16 sW[4][4 * RD * 8];     // 4 x 16 KB ring

    const int tid = threadIdx.x;
    const int lane = tid & 63;
    const int w = tid >> 6;          // 12 waves
    const int mg = w >> 1;           // 0..5 : 32-row group
    const int nh = w & 1;            // 0..1 : 128-col half
    const int l15 = lane & 15, l4 = lane >> 4;
    const int b = blockIdx.y;
    const int r_base = blockIdx.x * 192;
    const char* sXc = (const char*)uni;

    // ---- stage Xs[b] -> sXs (coalesced, chunk-swizzle cp^(r&7)) ----
    {
        const __bf16* src = Xs + (size_t)b * NRG * CS;
        #pragma unroll
        for (int it = 0; it < 3; ++it) {
            int id = it * 768 + tid;
            int r = id >> 6, cp = id & 63;
            bf16x8 v = *(const bf16x8*)(src + (size_t)r * CS + cp * 8);
            int ba = (r << 10) | ((cp ^ (r & 7)) << 4);
            *(bf16x8*)((char*)uni + ba) = v;
        }
    }
    const int t0 = r_base + mg * 32 + l15;
    const int ij0 = lut[t0], ij1 = lut[t0 + 16];
    const int i0 = ij0 >> 8, j0 = ij0 & 255;
    const int i1 = ij1 >> 8, j1 = ij1 & 255;

    asm volatile("s_waitcnt lgkmcnt(0)" ::: "memory");
    __builtin_amdgcn_s_barrier();     // sXs ready

    auto stg_t = [&](int t) {
        if (tid < 256) {
            const __bf16* src = (t < 16) ? (W1g + (size_t)t * (RD * 32))
                                         : (W2g + (size_t)(t - 16) * (RD * 32));
            __bf16* dst = &sW[t & 3][0];
            #pragma unroll
            for (int it = 0; it < 4; ++it) {
                int c = tid + it * 256;
                load_lds16(src + (size_t)c * 8, dst + (size_t)c * 8);
            }
        }
    };

    stg_t(0);
    stg_t(1);

    // ---- stage 1: tiles T0..T15 (K=512) ----
    f32x4 acc[2][8] = {};
    for (int t = 0; t < 16; ++t) {
        stg_t(t + 2);
        asm volatile("s_waitcnt vmcnt(8)" ::: "memory");
        __builtin_amdgcn_s_barrier();
        const int kc = t * 4 + l4;
        bf16x8 xi0 = *(const bf16x8*)(sXc + ((i0 << 10) | ((kc ^ (i0 & 7)) << 4)));
        bf16x8 xj0 = *(const bf16x8*)(sXc + ((j0 << 10) | ((kc ^ (j0 & 7)) << 4)));
        bf16x8 xi1 = *(const bf16x8*)(sXc + ((i1 << 10) | ((kc ^ (i1 & 7)) << 4)));
        bf16x8 xj1 = *(const bf16x8*)(sXc + ((j1 << 10) | ((kc ^ (j1 & 7)) << 4)));
        bf16x8 af0, af1;
        #pragma unroll
        for (int e = 0; e < 8; ++e) {
            af0[e] = (__bf16)((float)xi0[e] * (float)xj0[e]);
            af1[e] = (__bf16)((float)xi1[e] * (float)xj1[e]);
        }
        const __bf16* wb = &sW[t & 3][0];
        __builtin_amdgcn_s_setprio(1);
        #pragma unroll
        for (int g = 0; g < 8; ++g) {
            bf16x8 wf = *(const bf16x8*)(wb + ((size_t)l4 * RD + nh * 128 + g * 16 + l15) * 8);
            acc[0][g] = mfma16(af0, wf, acc[0][g]);
            acc[1][g] = mfma16(af1, wf, acc[1][g]);
        }
        __builtin_amdgcn_s_setprio(0);
    }

    __builtin_amdgcn_s_barrier();

    // ---- transition: H = relu(acc+b1) -> sH[kc2(32)][row(192)][8] ----
    #pragma unroll
    for (int g = 0; g < 8; ++g) {
        int col = nh * 128 + g * 16 + l15;
        float bb = b1[col];
        int kc2 = col >> 3, e = col & 7;
        #pragma unroll
        for (int fm = 0; fm < 2; ++fm) {
            int row0 = mg * 32 + fm * 16 + l4 * 4;
            #pragma unroll
            for (int r = 0; r < 4; ++r) {
                float v = fmaxf(acc[fm][g][r] + bb, 0.f);
                uni[((size_t)kc2 * 192 + row0 + r) * 8 + e] = (__bf16)v;
            }
        }
    }
    asm volatile("s_waitcnt lgkmcnt(0)" ::: "memory");
    __builtin_amdgcn_s_barrier();

    // ---- stage 2: tiles T16..T23 (W2, K=256) ----
    f32x4 acc2[2][8] = {};
    for (int t = 16; t < 24; ++t) {
        if (t + 2 < 24) stg_t(t + 2);
        if (t + 2 < 24)      asm volatile("s_waitcnt vmcnt(8)" ::: "memory");
        else if (t + 1 < 24) asm volatile("s_waitcnt vmcnt(4)" ::: "memory");
        else                 asm volatile("s_waitcnt vmcnt(0)" ::: "memory");
        __builtin_amdgcn_s_barrier();
        const int kt = t - 16;
        bf16x8 ah0, ah1;
        {
            int row0 = mg * 32 + l15;
            ah0 = *(const bf16x8*)(uni + ((size_t)(kt * 4 + l4) * 192 + row0) * 8);
            ah1 = *(const bf16x8*)(uni + ((size_t)(kt * 4 + l4) * 192 + row0 + 16) * 8);
        }
        const __bf16* wb = &sW[t & 3][0];
        __builtin_amdgcn_s_setprio(1);
        #pragma unroll
        for (int g = 0; g < 8; ++g) {
            bf16x8 wf = *(const bf16x8*)(wb + ((size_t)l4 * RD + nh * 128 + g * 16 + l15) * 8);
            acc2[0][g] = mfma16(ah0, wf, acc2[0][g]);
            acc2[1][g] = mfma16(ah1, wf, acc2[1][g]);
        }
        __builtin_amdgcn_s_setprio(0);
    }

    // ---- epilogue: acc2 -> LDS f32[96][256] -> 1KB contiguous stores ----
    float* uf = (float*)uni;
    float bias2[8];
    #pragma unroll
    for (int g = 0; g < 8; ++g) bias2[g] = b2[nh * 128 + g * 16 + l15];

    #pragma unroll
    for (int fm = 0; fm < 2; ++fm) {
        __syncthreads();
        #pragma unroll
        for (int g = 0; g < 8; ++g) {
            int col = nh * 128 + g * 16 + l15;
            #pragma unroll
            for (int r = 0; r < 4; ++r) {
                int row96 = mg * 16 + l4 * 4 + r;
                uf[(size_t)row96 * 256 + col] = fmaxf(acc2[fm][g][r] + bias2[g], 0.f);
            }
        }
        __syncthreads();
        #pragma unroll
        for (int k = 0; k < 8; ++k) {
            int row96 = w * 8 + k;
            int t = r_base + (row96 >> 4) * 32 + fm * 16 + (row96 & 15);
            if (t < TRI) {
                int ij = lut[t];
                int i = ij >> 8, j = ij & 255;
                f32x4 v = *(const f32x4*)&uf[(size_t)row96 * 256 + lane * 4];
                *(f32x4*)(Out + ((size_t)((b * NRG + i) * NRG + j)) * RD + lane * 4) = v;
                *(f32x4*)(Out + ((size_t)((b * NRG + j) * NRG + i)) * RD + lane * 4) = v;
            }
        }
    }
}

extern "C" void kernel_launch(void* const* d_in, const int* in_sizes, int n_in,
                              void* d_out, int out_size, void* d_ws, size_t ws_size,
                              hipStream_t stream) {
    const float* X   = (const float*)d_in[0];
    const float* Q   = (const float*)d_in[1];
    const float* pos = (const float*)d_in[2];
    const float* Wv  = (const float*)d_in[3];
    const float* bv  = (const float*)d_in[4];
    const float* Wq  = (const float*)d_in[5];
    const float* bq  = (const float*)d_in[6];
    const float* W1  = (const float*)d_in[7];
    const float* b1  = (const float*)d_in[8];
    const float* W2  = (const float*)d_in[9];
    const float* b2  = (const float*)d_in[10];

    char* ws = (char*)d_ws;
    size_t off = 0;
    auto alloc = [&](size_t bytes) {
        char* p = ws + off;
        off = (off + bytes + 255) & ~(size_t)255;
        return p;
    };
    __bf16* Xcg = (__bf16*)alloc((size_t)(KP/8) * MR * 8 * 2);   // 9.6 MB g-major
    __bf16* Wvg = (__bf16*)alloc((size_t)(KP/8) * CS * 8 * 2);
    __bf16* W1g = (__bf16*)alloc((size_t)(CS/8) * RD * 8 * 2);
    __bf16* W2g = (__bf16*)alloc((size_t)(RD/8) * RD * 8 * 2);
    float*  Qp  = (float*) alloc((size_t)BSZ * CS * 4);
    __bf16* Xs  = (__bf16*)alloc((size_t)MR * CS * 2);
    int*    lut = (int*)   alloc((size_t)TRIQ * 4);

    hipLaunchKernelGGL(k_prep, dim3(NXB + 616 + 1 + 512), dim3(256), 0, stream,
                       X, pos, Wv, W1, W2, Q, Wq, bq,
                       Xcg, Wvg, W1g, W2g, lut, Qp);
    hipLaunchKernelGGL(k_g1, dim3(MR/64, CS/64), dim3(256), 0, stream,
                       Xcg, Wvg, bv, Qp, Xs);
    hipLaunchKernelGGL(k_g23, dim3(TRIQ/192, BSZ), dim3(768), 0, stream,
                       Xs, W1g, W2g, b1, b2, (float*)d_out, (const int*)lut);
}